// Round 1
// baseline (11603.246 us; speedup 1.0000x reference)
//
#include <hip/hip_runtime.h>

#define Bx 64
#define Tx 512
#define Dx 1024
#define Ux 1024
#define Mx (Bx*Tx)   // 32768

typedef __attribute__((ext_vector_type(8))) short short8;
typedef __attribute__((ext_vector_type(4))) float f32x4;

static __device__ __forceinline__ unsigned short f2bf(float f){
  unsigned int u = __builtin_bit_cast(unsigned int, f);
  u = (u + 0x7FFFu + ((u >> 16) & 1u)) >> 16;
  return (unsigned short)u;
}
static __device__ __forceinline__ float bf2f(unsigned short s){
  unsigned int u = ((unsigned int)s) << 16;
  return __builtin_bit_cast(float, u);
}

// ---------------------------------------------------------------------------
// prep: W1T[n][k] = bf16(W1[k][n]); W2T[n][k] = bf16(W2[k][n])  (1024x1024)
// ---------------------------------------------------------------------------
__global__ __launch_bounds__(256) void prep_kernel(
    const float* __restrict__ W1, const float* __restrict__ W2,
    unsigned short* __restrict__ W1T, unsigned short* __restrict__ W2T)
{
  __shared__ unsigned short tile[64][72];   // +8 pad to break bank conflicts
  const float* src = blockIdx.y ? W2 : W1;
  unsigned short* dst = blockIdx.y ? W2T : W1T;
  const int bi = blockIdx.x >> 4;   // k tile
  const int bj = blockIdx.x & 15;   // n tile
  const int r  = threadIdx.x >> 2;        // 0..63
  const int c0 = (threadIdx.x & 3) * 16;  // 0,16,32,48
  for (int i = 0; i < 4; ++i){
    float4 v = *(const float4*)&src[(size_t)(bi*64 + r)*1024 + bj*64 + c0 + i*4];
    tile[r][c0+i*4+0] = f2bf(v.x);
    tile[r][c0+i*4+1] = f2bf(v.y);
    tile[r][c0+i*4+2] = f2bf(v.z);
    tile[r][c0+i*4+3] = f2bf(v.w);
  }
  __syncthreads();
  // write transposed, coalesced 16B stores
  unsigned short tmp[16];
  #pragma unroll
  for (int i = 0; i < 16; ++i) tmp[i] = tile[c0+i][r];
  unsigned int w[8];
  #pragma unroll
  for (int i = 0; i < 8; ++i) w[i] = (unsigned int)tmp[2*i] | ((unsigned int)tmp[2*i+1] << 16);
  unsigned short* o = &dst[(size_t)(bj*64 + r)*1024 + bi*64 + c0];
  *(uint4*)o       = make_uint4(w[0],w[1],w[2],w[3]);
  *(uint4*)(o + 8) = make_uint4(w[4],w[5],w[6],w[7]);
}

// ---------------------------------------------------------------------------
// gemm_h: h[m][n] = tanh( X[m][:] @ W1[:][n] + b1[n] ), fp32 out.
// bf16x2: X split hi/lo at stage time; W1 plain bf16 (pre-transposed W1T).
// 128x128 tile, BK=32, 256 threads (4 waves, each 64x64 quadrant).
// ---------------------------------------------------------------------------
__global__ __launch_bounds__(256) void gemm_h(
    const float* __restrict__ X, const unsigned short* __restrict__ W1T,
    const float* __restrict__ b1, float* __restrict__ h)
{
  __shared__ unsigned short Ah[128][40];  // pad 32->40: 2-way max conflicts
  __shared__ unsigned short Al[128][40];
  __shared__ unsigned short Bt[128][40];  // [n][k]
  const int m0 = blockIdx.x * 128, n0 = blockIdx.y * 128;
  const int tid = threadIdx.x;
  const int lane = tid & 63, wave = tid >> 6;
  const int mq = (wave >> 1) * 64, nq = (wave & 1) * 64;
  const int rs = tid >> 1, ks = (tid & 1) * 16;
  f32x4 z = {0.f, 0.f, 0.f, 0.f};
  f32x4 acc[4][4];
  for (int i = 0; i < 4; ++i) for (int j = 0; j < 4; ++j) acc[i][j] = z;

  const int mm = lane & 15, g = lane >> 4;
  for (int kc = 0; kc < 32; ++kc){
    const int kg = kc * 32;
    // stage X (fp32 -> bf16 hi/lo)
    {
      const float* xp = &X[(size_t)(m0 + rs)*1024 + kg + ks];
      #pragma unroll
      for (int i = 0; i < 4; ++i){
        float4 v = *(const float4*)(xp + i*4);
        unsigned short h0=f2bf(v.x), h1=f2bf(v.y), h2=f2bf(v.z), h3=f2bf(v.w);
        unsigned short l0=f2bf(v.x-bf2f(h0)), l1=f2bf(v.y-bf2f(h1));
        unsigned short l2=f2bf(v.z-bf2f(h2)), l3=f2bf(v.w-bf2f(h3));
        *(uint2*)&Ah[rs][ks+i*4] = make_uint2((unsigned)h0|((unsigned)h1<<16), (unsigned)h2|((unsigned)h3<<16));
        *(uint2*)&Al[rs][ks+i*4] = make_uint2((unsigned)l0|((unsigned)l1<<16), (unsigned)l2|((unsigned)l3<<16));
      }
      const unsigned short* wp = &W1T[(size_t)(n0 + rs)*1024 + kg + ks];
      *(uint4*)&Bt[rs][ks]     = *(const uint4*)wp;
      *(uint4*)&Bt[rs][ks + 8] = *(const uint4*)(wp + 8);
    }
    __syncthreads();
    short8 bf[4], ah[4], al[4];
    #pragma unroll
    for (int j = 0; j < 4; ++j) bf[j] = *(const short8*)&Bt[nq + j*16 + mm][g*8];
    #pragma unroll
    for (int i = 0; i < 4; ++i){
      ah[i] = *(const short8*)&Ah[mq + i*16 + mm][g*8];
      al[i] = *(const short8*)&Al[mq + i*16 + mm][g*8];
    }
    #pragma unroll
    for (int i = 0; i < 4; ++i)
      #pragma unroll
      for (int j = 0; j < 4; ++j){
        acc[i][j] = __builtin_amdgcn_mfma_f32_16x16x32_bf16(ah[i], bf[j], acc[i][j], 0, 0, 0);
        acc[i][j] = __builtin_amdgcn_mfma_f32_16x16x32_bf16(al[i], bf[j], acc[i][j], 0, 0, 0);
      }
    __syncthreads();
  }
  // epilogue: D layout col=lane&15, row=(lane>>4)*4+reg
  for (int i = 0; i < 4; ++i){
    const int mbase = m0 + mq + i*16 + g*4;
    for (int j = 0; j < 4; ++j){
      const int n = n0 + nq + j*16 + mm;
      const float bias = b1[n];
      #pragma unroll
      for (int r = 0; r < 4; ++r)
        h[(size_t)(mbase + r)*1024 + n] = tanhf(acc[i][j][r] + bias);
    }
  }
}

// ---------------------------------------------------------------------------
// rnn_scan: 256 WGs = 32 col-parts x 8 batch-parts, 128 threads (2 waves).
// W2 col-slice resident in LDS (bf16, XOR-swizzled). State ping-pong in
// global as bf16 hi/lo. Per-step barrier among the 32 WGs of a batch group.
// ---------------------------------------------------------------------------
__global__ __launch_bounds__(128) void rnn_scan(
    const unsigned short* __restrict__ W2T, const float* __restrict__ hbuf,
    const float* __restrict__ b2,
    unsigned short* s0h, unsigned short* s0l,
    unsigned short* s1h, unsigned short* s1l,
    unsigned int* cnt, unsigned short* __restrict__ feat)
{
  __shared__ unsigned short Wt[32][1024];   // 64 KB exactly
  const int wg = blockIdx.x;
  const int p = wg & 31, q = wg >> 5;   // p: col part (0..31), q: batch part (0..7)
  const int n0 = p * 32, b0 = q * 8;
  const int tid = threadIdx.x, lane = tid & 63, wv = tid >> 6;  // wv = j tile (0..1)

  // load W2T slice [n0..n0+32)[0..1024) with chunk-XOR swizzle
  for (int i = 0; i < 32; ++i){
    int f = i * 128 + tid;          // 4096 16B-chunks
    int n = f >> 7, c = f & 127;
    uint4 v = *(const uint4*)&W2T[(size_t)(n0 + n)*1024 + c*8];
    int cs = c ^ (n & 7);
    *(uint4*)&Wt[n][cs*8] = v;
  }
  __syncthreads();

  const int mm = lane & 15, g = lane >> 4;
  const int arow = b0 + (lane & 7);        // valid rows 0..7, rows 8..15 duplicate
  const int nloc = wv*16 + mm;             // 0..31

  #pragma unroll 1
  for (int t = 0; t < 512; ++t){
    const unsigned short* rh = (t & 1) ? s1h : s0h;
    const unsigned short* rl = (t & 1) ? s1l : s0l;
    unsigned short* wh = (t & 1) ? s0h : s1h;
    unsigned short* wl = (t & 1) ? s0l : s1l;

    f32x4 a0 = {0,0,0,0}, a1 = {0,0,0,0}, a2 = {0,0,0,0}, a3 = {0,0,0,0};
    for (int ks = 0; ks < 32; ks += 2){
      int k0 = ks * 32;
      short8 ah0 = *(const short8*)&rh[arow*1024 + k0 + g*8];
      short8 al0 = *(const short8*)&rl[arow*1024 + k0 + g*8];
      short8 ah1 = *(const short8*)&rh[arow*1024 + k0 + 32 + g*8];
      short8 al1 = *(const short8*)&rl[arow*1024 + k0 + 32 + g*8];
      int c0 = (k0 >> 3) + g, c1 = c0 + 4;
      short8 b0f = *(const short8*)&Wt[nloc][(c0 ^ (nloc & 7))*8];
      short8 b1f = *(const short8*)&Wt[nloc][(c1 ^ (nloc & 7))*8];
      a0 = __builtin_amdgcn_mfma_f32_16x16x32_bf16(ah0, b0f, a0, 0,0,0);
      a1 = __builtin_amdgcn_mfma_f32_16x16x32_bf16(al0, b0f, a1, 0,0,0);
      a2 = __builtin_amdgcn_mfma_f32_16x16x32_bf16(ah1, b1f, a2, 0,0,0);
      a3 = __builtin_amdgcn_mfma_f32_16x16x32_bf16(al1, b1f, a3, 0,0,0);
    }
    f32x4 acc;
    acc = a0 + a1 + a2 + a3;

    // epilogue: lanes 0..31 hold rows (lane>>4)*4 + r (0..7), col = lane&15
    if (lane < 32){
      const int n = n0 + wv*16 + (lane & 15);
      const float bias = b2[n];
      const int rbase = (lane >> 4) * 4;
      #pragma unroll
      for (int r = 0; r < 4; ++r){
        const int b = b0 + rbase + r;
        const float pre = acc[r] + bias;
        const float y = hbuf[(size_t)b*Tx*Ux + (size_t)t*Ux + n] + tanhf(pre);
        unsigned short yh = f2bf(y);
        unsigned short yl = f2bf(y - bf2f(yh));
        wh[b*1024 + n] = yh;
        wl[b*1024 + n] = yl;
        feat[(size_t)b*Tx*Ux + (size_t)t*Ux + n] = yh;
      }
    }
    __syncthreads();
    if (tid == 0){
      __threadfence();
      unsigned int* c = &cnt[q*512 + t];
      __hip_atomic_fetch_add(c, 1u, __ATOMIC_RELEASE, __HIP_MEMORY_SCOPE_AGENT);
      while (__hip_atomic_load(c, __ATOMIC_RELAXED, __HIP_MEMORY_SCOPE_AGENT) < 32u)
        __builtin_amdgcn_s_sleep(2);
      __threadfence();
    }
    __syncthreads();
  }
}

// ---------------------------------------------------------------------------
// proj_out: out[m] = feat[m][:] (bf16) . Wc (fp32) + bc
// ---------------------------------------------------------------------------
__global__ __launch_bounds__(256) void proj_out(
    const unsigned short* __restrict__ feat, const float* __restrict__ Wc,
    const float* __restrict__ bc, float* __restrict__ out)
{
  const int wv = threadIdx.x >> 6, lane = threadIdx.x & 63;
  const int m = blockIdx.x * 4 + wv;
  const unsigned short* fp = &feat[(size_t)m*1024 + lane*16];
  float s = 0.f;
  #pragma unroll
  for (int i = 0; i < 2; ++i){
    uint4 v = *(const uint4*)(fp + i*8);
    float4 w0 = *(const float4*)&Wc[lane*16 + i*8];
    float4 w1 = *(const float4*)&Wc[lane*16 + i*8 + 4];
    unsigned int vv[4] = {v.x, v.y, v.z, v.w};
    s += bf2f((unsigned short)(vv[0] & 0xFFFF))*w0.x + bf2f((unsigned short)(vv[0] >> 16))*w0.y;
    s += bf2f((unsigned short)(vv[1] & 0xFFFF))*w0.z + bf2f((unsigned short)(vv[1] >> 16))*w0.w;
    s += bf2f((unsigned short)(vv[2] & 0xFFFF))*w1.x + bf2f((unsigned short)(vv[2] >> 16))*w1.y;
    s += bf2f((unsigned short)(vv[3] & 0xFFFF))*w1.z + bf2f((unsigned short)(vv[3] >> 16))*w1.w;
  }
  for (int o = 32; o; o >>= 1) s += __shfl_down(s, o);
  if (lane == 0) out[m] = s + bc[0];
}

// ---------------------------------------------------------------------------
extern "C" void kernel_launch(void* const* d_in, const int* in_sizes, int n_in,
                              void* d_out, int out_size, void* d_ws, size_t ws_size,
                              hipStream_t stream)
{
  (void)in_sizes; (void)n_in; (void)out_size; (void)ws_size;
  const float* X  = (const float*)d_in[0];
  const float* W1 = (const float*)d_in[1];
  const float* b1 = (const float*)d_in[2];
  const float* W2 = (const float*)d_in[3];
  const float* b2 = (const float*)d_in[4];
  const float* Wc = (const float*)d_in[5];
  const float* bc = (const float*)d_in[6];
  float* out = (float*)d_out;
  char* ws = (char*)d_ws;

  unsigned short* W1T = (unsigned short*)(ws + 0);
  unsigned short* W2T = (unsigned short*)(ws + 2097152);
  unsigned short* s0h = (unsigned short*)(ws + 4194304);
  unsigned short* s0l = (unsigned short*)(ws + 4194304 + 131072);
  unsigned short* s1h = (unsigned short*)(ws + 4194304 + 262144);
  unsigned short* s1l = (unsigned short*)(ws + 4194304 + 393216);
  unsigned int*  cnt = (unsigned int*) (ws + 4718592);            // 16 KB
  float* hbuf         = (float*)        (ws + 4734976);            // 128 MiB
  unsigned short* feat = (unsigned short*)(ws + 4734976 + 134217728); // 64 MiB

  // zero state ping-pong buffers + barrier counters (contiguous region)
  hipMemsetAsync(s0h, 0, 524288 + 16384, stream);

  prep_kernel<<<dim3(256, 2), 256, 0, stream>>>(W1, W2, W1T, W2T);
  gemm_h<<<dim3(Mx/128, Ux/128), 256, 0, stream>>>(X, W1T, b1, hbuf);

  void* args[] = { (void*)&W2T, (void*)&hbuf, (void*)&b2,
                   (void*)&s0h, (void*)&s0l, (void*)&s1h, (void*)&s1l,
                   (void*)&cnt, (void*)&feat };
  hipLaunchCooperativeKernel((void*)rnn_scan, dim3(256), dim3(128), args, 0, stream);

  proj_out<<<Mx/4, 256, 0, stream>>>(feat, Wc, bc, out);
}

// Round 2
// 5866.162 us; speedup vs baseline: 1.9780x; 1.9780x over previous
//
#include <hip/hip_runtime.h>

#define Bx 64
#define Tx 512
#define Dx 1024
#define Ux 1024
#define Mx (Bx*Tx)   // 32768

typedef __attribute__((ext_vector_type(8))) short short8;
typedef __attribute__((ext_vector_type(4))) float f32x4;

static __device__ __forceinline__ unsigned short f2bf(float f){
  unsigned int u = __builtin_bit_cast(unsigned int, f);
  u = (u + 0x7FFFu + ((u >> 16) & 1u)) >> 16;
  return (unsigned short)u;
}
static __device__ __forceinline__ float bf2f(unsigned short s){
  unsigned int u = ((unsigned int)s) << 16;
  return __builtin_bit_cast(float, u);
}

// ---------------------------------------------------------------------------
// prep: W1T[n][k] = bf16(W1[k][n]); W2T[n][k] = bf16(W2[k][n])  (1024x1024)
// ---------------------------------------------------------------------------
__global__ __launch_bounds__(256) void prep_kernel(
    const float* __restrict__ W1, const float* __restrict__ W2,
    unsigned short* __restrict__ W1T, unsigned short* __restrict__ W2T)
{
  __shared__ unsigned short tile[64][72];
  const float* src = blockIdx.y ? W2 : W1;
  unsigned short* dst = blockIdx.y ? W2T : W1T;
  const int bi = blockIdx.x >> 4;
  const int bj = blockIdx.x & 15;
  const int r  = threadIdx.x >> 2;
  const int c0 = (threadIdx.x & 3) * 16;
  for (int i = 0; i < 4; ++i){
    float4 v = *(const float4*)&src[(size_t)(bi*64 + r)*1024 + bj*64 + c0 + i*4];
    tile[r][c0+i*4+0] = f2bf(v.x);
    tile[r][c0+i*4+1] = f2bf(v.y);
    tile[r][c0+i*4+2] = f2bf(v.z);
    tile[r][c0+i*4+3] = f2bf(v.w);
  }
  __syncthreads();
  unsigned short tmp[16];
  #pragma unroll
  for (int i = 0; i < 16; ++i) tmp[i] = tile[c0+i][r];
  unsigned int w[8];
  #pragma unroll
  for (int i = 0; i < 8; ++i) w[i] = (unsigned int)tmp[2*i] | ((unsigned int)tmp[2*i+1] << 16);
  unsigned short* o = &dst[(size_t)(bj*64 + r)*1024 + bi*64 + c0];
  *(uint4*)o       = make_uint4(w[0],w[1],w[2],w[3]);
  *(uint4*)(o + 8) = make_uint4(w[4],w[5],w[6],w[7]);
}

// ---------------------------------------------------------------------------
// gemm_h: h[m][n] = tanh( X[m][:] @ W1[:][n] + b1[n] ), fp32 out. (unchanged)
// ---------------------------------------------------------------------------
__global__ __launch_bounds__(256) void gemm_h(
    const float* __restrict__ X, const unsigned short* __restrict__ W1T,
    const float* __restrict__ b1, float* __restrict__ h)
{
  __shared__ unsigned short Ah[128][40];
  __shared__ unsigned short Al[128][40];
  __shared__ unsigned short Bt[128][40];
  const int m0 = blockIdx.x * 128, n0 = blockIdx.y * 128;
  const int tid = threadIdx.x;
  const int lane = tid & 63, wave = tid >> 6;
  const int mq = (wave >> 1) * 64, nq = (wave & 1) * 64;
  const int rs = tid >> 1, ks = (tid & 1) * 16;
  f32x4 z = {0.f, 0.f, 0.f, 0.f};
  f32x4 acc[4][4];
  for (int i = 0; i < 4; ++i) for (int j = 0; j < 4; ++j) acc[i][j] = z;

  const int mm = lane & 15, g = lane >> 4;
  for (int kc = 0; kc < 32; ++kc){
    const int kg = kc * 32;
    {
      const float* xp = &X[(size_t)(m0 + rs)*1024 + kg + ks];
      #pragma unroll
      for (int i = 0; i < 4; ++i){
        float4 v = *(const float4*)(xp + i*4);
        unsigned short h0=f2bf(v.x), h1=f2bf(v.y), h2=f2bf(v.z), h3=f2bf(v.w);
        unsigned short l0=f2bf(v.x-bf2f(h0)), l1=f2bf(v.y-bf2f(h1));
        unsigned short l2=f2bf(v.z-bf2f(h2)), l3=f2bf(v.w-bf2f(h3));
        *(uint2*)&Ah[rs][ks+i*4] = make_uint2((unsigned)h0|((unsigned)h1<<16), (unsigned)h2|((unsigned)h3<<16));
        *(uint2*)&Al[rs][ks+i*4] = make_uint2((unsigned)l0|((unsigned)l1<<16), (unsigned)l2|((unsigned)l3<<16));
      }
      const unsigned short* wp = &W1T[(size_t)(n0 + rs)*1024 + kg + ks];
      *(uint4*)&Bt[rs][ks]     = *(const uint4*)wp;
      *(uint4*)&Bt[rs][ks + 8] = *(const uint4*)(wp + 8);
    }
    __syncthreads();
    short8 bf[4], ah[4], al[4];
    #pragma unroll
    for (int j = 0; j < 4; ++j) bf[j] = *(const short8*)&Bt[nq + j*16 + mm][g*8];
    #pragma unroll
    for (int i = 0; i < 4; ++i){
      ah[i] = *(const short8*)&Ah[mq + i*16 + mm][g*8];
      al[i] = *(const short8*)&Al[mq + i*16 + mm][g*8];
    }
    #pragma unroll
    for (int i = 0; i < 4; ++i)
      #pragma unroll
      for (int j = 0; j < 4; ++j){
        acc[i][j] = __builtin_amdgcn_mfma_f32_16x16x32_bf16(ah[i], bf[j], acc[i][j], 0, 0, 0);
        acc[i][j] = __builtin_amdgcn_mfma_f32_16x16x32_bf16(al[i], bf[j], acc[i][j], 0, 0, 0);
      }
    __syncthreads();
  }
  for (int i = 0; i < 4; ++i){
    const int mbase = m0 + mq + i*16 + g*4;
    for (int j = 0; j < 4; ++j){
      const int n = n0 + nq + j*16 + mm;
      const float bias = b1[n];
      #pragma unroll
      for (int r = 0; r < 4; ++r)
        h[(size_t)(mbase + r)*1024 + n] = tanhf(acc[i][j][r] + bias);
    }
  }
}

// ---------------------------------------------------------------------------
// rnn_scan v2: fence-free. State exchanged as packed (hi<<16|lo) dwords via
// RELAXED agent-scope atomics (coherent at MALL, no L2 flush). Flag = relaxed
// atomic counter; data->flag ordering via the vmcnt(0) drain inside
// __syncthreads. State staged into LDS (hi/lo planes, bank-padded).
// 256 WGs = 32 col-parts x 8 batch-parts, 128 threads.
// ---------------------------------------------------------------------------
__global__ __launch_bounds__(128) void rnn_scan(
    const unsigned short* __restrict__ W2T, const float* __restrict__ hbuf,
    const float* __restrict__ b2,
    unsigned int* s0, unsigned int* s1,
    unsigned int* cnt, unsigned short* __restrict__ feat)
{
  __shared__ unsigned short Wt[32][1024];   // 64 KB, XOR-swizzled
  __shared__ unsigned short Shi[8][1040];   // 16.6 KB, pad: rows spread banks
  __shared__ unsigned short Slo[8][1040];   // 16.6 KB
  const int wg = blockIdx.x;
  const int p = wg & 31, q = wg >> 5;
  const int n0 = p * 32, b0 = q * 8;
  const int tid = threadIdx.x, lane = tid & 63, wv = tid >> 6;

  // load W2T slice [n0..n0+32)[0..1024) with chunk-XOR swizzle
  for (int i = 0; i < 32; ++i){
    int f = i * 128 + tid;
    int n = f >> 7, c = f & 127;
    uint4 v = *(const uint4*)&W2T[(size_t)(n0 + n)*1024 + c*8];
    int cs = c ^ (n & 7);
    *(uint4*)&Wt[n][cs*8] = v;
  }

  const int mm = lane & 15, g = lane >> 4;
  const int r8 = lane & 7;
  const int nloc = wv*16 + mm;

  #pragma unroll 1
  for (int t = 0; t < 512; ++t){
    const unsigned int* rsg = (t & 1) ? s1 : s0;
    unsigned int* wsb = (t & 1) ? s0 : s1;

    // prefetch hbuf[t] (independent of state) before the poll
    float hv[4];
    if (lane < 32){
      const int n = n0 + wv*16 + mm;
      const int rbase = g * 4;
      #pragma unroll
      for (int r = 0; r < 4; ++r)
        hv[r] = hbuf[(size_t)(b0 + rbase + r)*Tx*Ux + (size_t)t*Ux + n];
    }

    // wait for step t-1 producers (t=0 reads zero-init s0: no wait)
    if (t > 0){
      const unsigned int* c = &cnt[q*512 + (t-1)];
      while (__hip_atomic_load(c, __ATOMIC_RELAXED, __HIP_MEMORY_SCOPE_AGENT) < 32u)
        __builtin_amdgcn_s_sleep(1);
    }
    asm volatile("" ::: "memory");

    // state -> LDS, split into hi/lo bf16 planes (atomic dword loads: fresh
    // at device coherence point, no fence needed for relaxed atomics)
    {
      const unsigned int* sp = rsg + (size_t)b0 * 1024;
      #pragma unroll 8
      for (int i = 0; i < 32; ++i){
        const int f0 = i*256 + tid*2;
        unsigned int d0 = __hip_atomic_load(sp + f0,     __ATOMIC_RELAXED, __HIP_MEMORY_SCOPE_AGENT);
        unsigned int d1 = __hip_atomic_load(sp + f0 + 1, __ATOMIC_RELAXED, __HIP_MEMORY_SCOPE_AGENT);
        const int row = f0 >> 10, col = f0 & 1023;
        *(unsigned int*)&Shi[row][col] = (d0 >> 16)      | (d1 & 0xffff0000u);
        *(unsigned int*)&Slo[row][col] = (d0 & 0xffffu)  | (d1 << 16);
      }
    }
    __syncthreads();   // Sd planes visible to both waves (also first-iter Wt)

    f32x4 a0 = {0,0,0,0}, a1 = {0,0,0,0}, a2 = {0,0,0,0}, a3 = {0,0,0,0};
    #pragma unroll
    for (int ks = 0; ks < 32; ks += 2){
      const int k0 = ks * 32;
      short8 ah0 = *(const short8*)&Shi[r8][k0 + g*8];
      short8 al0 = *(const short8*)&Slo[r8][k0 + g*8];
      short8 ah1 = *(const short8*)&Shi[r8][k0 + 32 + g*8];
      short8 al1 = *(const short8*)&Slo[r8][k0 + 32 + g*8];
      const int c0 = (k0 >> 3) + g, c1 = c0 + 4;
      short8 b0f = *(const short8*)&Wt[nloc][(c0 ^ (nloc & 7))*8];
      short8 b1f = *(const short8*)&Wt[nloc][(c1 ^ (nloc & 7))*8];
      a0 = __builtin_amdgcn_mfma_f32_16x16x32_bf16(ah0, b0f, a0, 0,0,0);
      a1 = __builtin_amdgcn_mfma_f32_16x16x32_bf16(al0, b0f, a1, 0,0,0);
      a2 = __builtin_amdgcn_mfma_f32_16x16x32_bf16(ah1, b1f, a2, 0,0,0);
      a3 = __builtin_amdgcn_mfma_f32_16x16x32_bf16(al1, b1f, a3, 0,0,0);
    }
    f32x4 acc = a0 + a1 + a2 + a3;

    // epilogue: lanes<32 hold rows g*4+r (0..7), col = lane&15
    if (lane < 32){
      const int n = n0 + wv*16 + mm;
      const float bias = b2[n];
      const int rbase = g * 4;
      #pragma unroll
      for (int r = 0; r < 4; ++r){
        const int b = b0 + rbase + r;
        const float y = hv[r] + tanhf(acc[r] + bias);
        unsigned short yh = f2bf(y);
        unsigned short yl = f2bf(y - bf2f(yh));
        __hip_atomic_store(&wsb[b*1024 + n], ((unsigned int)yh << 16) | (unsigned int)yl,
                           __ATOMIC_RELAXED, __HIP_MEMORY_SCOPE_AGENT);
        feat[(size_t)b*Tx*Ux + (size_t)t*Ux + n] = yh;
      }
    }
    // __syncthreads drains vmcnt(0) per wave before s_barrier -> after it,
    // BOTH waves' atomic stores have reached the coherence point.
    __syncthreads();
    if (tid == 0)
      __hip_atomic_fetch_add(&cnt[q*512 + t], 1u, __ATOMIC_RELAXED, __HIP_MEMORY_SCOPE_AGENT);
  }
}

// ---------------------------------------------------------------------------
// proj_out: out[m] = feat[m][:] (bf16) . Wc (fp32) + bc
// ---------------------------------------------------------------------------
__global__ __launch_bounds__(256) void proj_out(
    const unsigned short* __restrict__ feat, const float* __restrict__ Wc,
    const float* __restrict__ bc, float* __restrict__ out)
{
  const int wv = threadIdx.x >> 6, lane = threadIdx.x & 63;
  const int m = blockIdx.x * 4 + wv;
  const unsigned short* fp = &feat[(size_t)m*1024 + lane*16];
  float s = 0.f;
  #pragma unroll
  for (int i = 0; i < 2; ++i){
    uint4 v = *(const uint4*)(fp + i*8);
    float4 w0 = *(const float4*)&Wc[lane*16 + i*8];
    float4 w1 = *(const float4*)&Wc[lane*16 + i*8 + 4];
    unsigned int vv[4] = {v.x, v.y, v.z, v.w};
    s += bf2f((unsigned short)(vv[0] & 0xFFFF))*w0.x + bf2f((unsigned short)(vv[0] >> 16))*w0.y;
    s += bf2f((unsigned short)(vv[1] & 0xFFFF))*w0.z + bf2f((unsigned short)(vv[1] >> 16))*w0.w;
    s += bf2f((unsigned short)(vv[2] & 0xFFFF))*w1.x + bf2f((unsigned short)(vv[2] >> 16))*w1.y;
    s += bf2f((unsigned short)(vv[3] & 0xFFFF))*w1.z + bf2f((unsigned short)(vv[3] >> 16))*w1.w;
  }
  for (int o = 32; o; o >>= 1) s += __shfl_down(s, o);
  if (lane == 0) out[m] = s + bc[0];
}

// ---------------------------------------------------------------------------
extern "C" void kernel_launch(void* const* d_in, const int* in_sizes, int n_in,
                              void* d_out, int out_size, void* d_ws, size_t ws_size,
                              hipStream_t stream)
{
  (void)in_sizes; (void)n_in; (void)out_size; (void)ws_size;
  const float* X  = (const float*)d_in[0];
  const float* W1 = (const float*)d_in[1];
  const float* b1 = (const float*)d_in[2];
  const float* W2 = (const float*)d_in[3];
  const float* b2 = (const float*)d_in[4];
  const float* Wc = (const float*)d_in[5];
  const float* bc = (const float*)d_in[6];
  float* out = (float*)d_out;
  char* ws = (char*)d_ws;

  unsigned short* W1T = (unsigned short*)(ws + 0);          // 2 MiB
  unsigned short* W2T = (unsigned short*)(ws + 2097152);    // 2 MiB
  unsigned int*   s0  = (unsigned int*)  (ws + 4194304);    // 256 KiB (packed state)
  unsigned int*   s1  = (unsigned int*)  (ws + 4456448);    // 256 KiB
  unsigned int*   cnt = (unsigned int*)  (ws + 4718592);    // 16 KiB
  float* hbuf         = (float*)         (ws + 4734976);    // 128 MiB
  unsigned short* feat = (unsigned short*)(ws + 4734976 + 134217728); // 64 MiB

  // zero s0 + s1 + cnt (contiguous 528 KiB)
  hipMemsetAsync(s0, 0, 262144 + 262144 + 16384, stream);

  prep_kernel<<<dim3(256, 2), 256, 0, stream>>>(W1, W2, W1T, W2T);
  gemm_h<<<dim3(Mx/128, Ux/128), 256, 0, stream>>>(X, W1T, b1, hbuf);

  void* args[] = { (void*)&W2T, (void*)&hbuf, (void*)&b2,
                   (void*)&s0, (void*)&s1, (void*)&cnt, (void*)&feat };
  hipLaunchCooperativeKernel((void*)rnn_scan, dim3(256), dim3(128), args, 0, stream);

  proj_out<<<Mx/4, 256, 0, stream>>>(feat, Wc, bc, out);
}